// Round 6
// baseline (194.967 us; speedup 1.0000x reference)
//
#include <hip/hip_runtime.h>

// Fused: LayerNorm -> QKV proj -> per-head attention (diag masked) -> out proj
// B=2, N=2048, D=1024, H=16, dh=64. bf16 MFMA 16x16x32 everywhere.
// R16: attn occupancy 4->6 waves/SIMD. R15 (2->4 waves/SIMD) gave +7%;
//     occupancy is the proven lever and grid size is the binding constraint
//     (VGPR=64, LDS would allow 3 blocks/CU but grid 512 = 2/CU exact).
//     Split q-tile 128->64: grid (32 bh, 32 qt) = 1024 blocks, 512 thr/8 wv,
//     wave = (ikv half, jq in 4x16q). LDS 42.2KB -> 3 blocks/CU = 24 wv/CU.
//     Per-CU MFMA/exp2 totals unchanged; staging volume x1.5 (L2-served).

#define DIMM   1024
#define NSEQ   2048
#define BATCH  2
#define HEADS  16
#define DHEAD  64
#define QKVN   3072
#define MROWS  4096   // BATCH*NSEQ

typedef float          f32x4  __attribute__((ext_vector_type(4)));
typedef __bf16         bf16x8 __attribute__((ext_vector_type(8)));
typedef __bf16         bf16x4 __attribute__((ext_vector_type(4)));
typedef unsigned short u16x8  __attribute__((ext_vector_type(8)));
typedef unsigned short u16x4  __attribute__((ext_vector_type(4)));

// SCALE * log2(e): fold into q so softmax uses exp2 directly.
#define QSCALE (0.125f * 1.4426950408889634f)

#if __has_builtin(__builtin_amdgcn_exp2f)
#define EXP2(x) __builtin_amdgcn_exp2f(x)
#else
#define EXP2(x) exp2f(x)
#endif

__device__ __forceinline__ unsigned short f2bf(float f) {
  unsigned u = __builtin_bit_cast(unsigned, f);
  u += 0x7FFFu + ((u >> 16) & 1u);   // round-to-nearest-even
  return (unsigned short)(u >> 16);
}
__device__ __forceinline__ bf16x8 as_bf(u16x8 v) { return __builtin_bit_cast(bf16x8, v); }

// f32x4 -> 4 bf16 (RNE)
__device__ __forceinline__ u16x4 cvt4(f32x4 v) {
  bf16x4 b;
  b[0] = (__bf16)v[0]; b[1] = (__bf16)v[1]; b[2] = (__bf16)v[2]; b[3] = (__bf16)v[3];
  return __builtin_bit_cast(u16x4, b);
}

// async global->LDS, 16B per lane; LDS dest = wave-uniform base + lane*16
__device__ __forceinline__ void gl_lds16(const unsigned short* g, unsigned short* l) {
  __builtin_amdgcn_global_load_lds(
      (const __attribute__((address_space(1))) unsigned*)g,
      (__attribute__((address_space(3))) unsigned*)l, 16, 0, 0);
}

// swizzled b128 fragment read from an unpadded [rows][64] bf16 tile:
// LDS chunk c at row r holds global chunk c ^ (r&7).
__device__ __forceinline__ bf16x8 lds_frag(const unsigned short* base, int row, int chunk) {
  return as_bf(*(const u16x8*)&base[row * 64 + ((chunk ^ (row & 7)) << 3)]);
}

// same for [rows][128] bf16 tiles (16 chunks/row, 4-bit xor)
__device__ __forceinline__ bf16x8 lds_frag128(const unsigned short* base, int row, int chunk) {
  return as_bf(*(const u16x8*)&base[row * 128 + ((chunk ^ (row & 15)) << 3)]);
}

// ---------------- weight transpose tile + fp32->bf16: dst[c][r] = src[r][c]
__device__ __forceinline__ void transpose_tile(
    const float* __restrict__ src, unsigned short* __restrict__ dst,
    int R, int C, int bx, int by, int tid) {
  __shared__ float t[32][33];
  const int rb = by * 32, cb = bx * 32;
  const int r0 = tid >> 5;   // 0..7
  const int c  = tid & 31;
#pragma unroll
  for (int i = 0; i < 4; ++i)
    t[r0 + i * 8][c] = src[(rb + r0 + i * 8) * C + cb + c];
  __syncthreads();
#pragma unroll
  for (int i = 0; i < 4; ++i)
    dst[(cb + r0 + i * 8) * R + rb + c] = f2bf(t[c][r0 + i * 8]);
}

// ---------------- prep: LN (blocks 0..4095) + weight transposes (4096..8191)
__global__ __launch_bounds__(256) void prep_kernel(
    const float* __restrict__ x, const float* __restrict__ g,
    const float* __restrict__ be, const float* __restrict__ w_qkv,
    const float* __restrict__ w_out, unsigned short* __restrict__ xn,
    unsigned short* __restrict__ wqkvT, unsigned short* __restrict__ woutT) {
  const int bid = blockIdx.x, tid = threadIdx.x;
  if (bid < MROWS) {
    // LayerNorm: one row (1024) per 256-thread block, bf16 out
    const int row = bid;
    const int wave = tid >> 6, lane = tid & 63;
    const float4 v = *(const float4*)&x[row * DIMM + tid * 4];
    float s  = v.x + v.y + v.z + v.w;
    float s2 = v.x * v.x + v.y * v.y + v.z * v.z + v.w * v.w;
#pragma unroll
    for (int o = 32; o >= 1; o >>= 1) { s += __shfl_xor(s, o); s2 += __shfl_xor(s2, o); }
    __shared__ float ps[4], ps2[4];
    if (lane == 0) { ps[wave] = s; ps2[wave] = s2; }
    __syncthreads();
    s  = ps[0] + ps[1] + ps[2] + ps[3];
    s2 = ps2[0] + ps2[1] + ps2[2] + ps2[3];
    const float mu  = s * (1.0f / DIMM);
    const float var = s2 * (1.0f / DIMM) - mu * mu;
    const float rs  = rsqrtf(var + 1e-5f);
    const float4 gg = *(const float4*)&g[tid * 4];
    const float4 bb = *(const float4*)&be[tid * 4];
    u16x4 o;
    o[0] = f2bf((v.x - mu) * rs * gg.x + bb.x);
    o[1] = f2bf((v.y - mu) * rs * gg.y + bb.y);
    o[2] = f2bf((v.z - mu) * rs * gg.z + bb.z);
    o[3] = f2bf((v.w - mu) * rs * gg.w + bb.w);
    *(u16x4*)&xn[row * DIMM + tid * 4] = o;
  } else {
    const int t = bid - MROWS;            // 0..4095
    const int bx = t & 127, by = t >> 7;  // 128 x 32
    if (bx < QKVN / 32) transpose_tile(w_qkv, wqkvT, DIMM, QKVN, bx, by, tid);
    else                transpose_tile(w_out, woutT, DIMM, DIMM, bx - QKVN / 32, by, tid);
  }
}

// ---------------- merged QKV GEMM: 128x128 tiles, single-buffer 32KB LDS,
// 3 blocks/CU co-resident (grid 768). bn 0..15 -> q/k (C^T), 16..23 -> v (C).
__global__ __launch_bounds__(256, 3) void gemm_qkv_kernel(
    const unsigned short* __restrict__ A, const unsigned short* __restrict__ Bt,
    unsigned short* __restrict__ qb, unsigned short* __restrict__ kb,
    unsigned short* __restrict__ vtb) {
  __shared__ __attribute__((aligned(16))) unsigned short As[128 * 64];  // 16 KB
  __shared__ __attribute__((aligned(16))) unsigned short Bs[128 * 64];  // 16 KB
  const int tid = threadIdx.x;
  const int bm = blockIdx.y, bn = blockIdx.x;
  const int lane = tid & 63, wave = tid >> 6;
  const int l15 = lane & 15, quad = lane >> 4;
  const int wm = wave >> 1, wn = wave & 1;
  const int lrow = lane >> 3;
  const int gcol = ((lane & 7) ^ lrow) << 3;
  const unsigned short* Ab = A  + (bm * 128 + wave * 32 + lrow) * DIMM + gcol;
  const unsigned short* Bb = Bt + (bn * 128 + wave * 32 + lrow) * DIMM + gcol;
  const bool swap = (bn < 16);
  f32x4 acc[4][4] = {};

  for (int k0 = 0; k0 < DIMM; k0 += 64) {
#pragma unroll
    for (int j = 0; j < 4; ++j) {
      gl_lds16(Ab + j * 8 * DIMM + k0, &As[(wave * 32 + j * 8) * 64]);
      gl_lds16(Bb + j * 8 * DIMM + k0, &Bs[(wave * 32 + j * 8) * 64]);
    }
    __syncthreads();
#pragma unroll
    for (int kk = 0; kk < 2; ++kk) {
      bf16x8 af[4], bfr[4];
#pragma unroll
      for (int mi = 0; mi < 4; ++mi) af[mi]  = lds_frag(As, wm * 64 + mi * 16 + l15, kk * 4 + quad);
#pragma unroll
      for (int ni = 0; ni < 4; ++ni) bfr[ni] = lds_frag(Bs, wn * 64 + ni * 16 + l15, kk * 4 + quad);
      if (swap) {
#pragma unroll
        for (int mi = 0; mi < 4; ++mi)
#pragma unroll
          for (int ni = 0; ni < 4; ++ni)
            acc[mi][ni] = __builtin_amdgcn_mfma_f32_16x16x32_bf16(bfr[ni], af[mi], acc[mi][ni], 0, 0, 0);
      } else {
#pragma unroll
        for (int mi = 0; mi < 4; ++mi)
#pragma unroll
          for (int ni = 0; ni < 4; ++ni)
            acc[mi][ni] = __builtin_amdgcn_mfma_f32_16x16x32_bf16(af[mi], bfr[ni], acc[mi][ni], 0, 0, 0);
      }
    }
    __syncthreads();
  }

  if (swap) {
    // q/k blocks: C^T -> reg r runs along weight col (dd) -> b64 stores.
    const int colbase = bn * 128 + wn * 64;        // wave-uniform
    const int which = colbase >> 10;               // 0=q, 1=k
    unsigned short* dst = which ? kb : qb;
    const float sc = which ? 1.0f : QSCALE;
#pragma unroll
    for (int mi = 0; mi < 4; ++mi) {
      const int m = bm * 128 + wm * 64 + mi * 16 + l15;   // xn row
      const int bh0 = (m >> 11) * HEADS;
      const int n = m & 2047;
#pragma unroll
      for (int ni = 0; ni < 4; ++ni) {
        const int wc = (colbase & 1023) + ni * 16 + quad * 4;  // r-contig
        const int h = wc >> 6, dd = wc & 63;
        f32x4 v = acc[mi][ni] * sc;
        *(u16x4*)&dst[((bh0 + h) * NSEQ + n) * DHEAD + dd] = cvt4(v);
      }
    }
  } else {
    // v blocks: C -> reg r runs along n -> b64 stores to vt.
    const int colbase = bn * 128 + wn * 64 - 2048;   // v col base, 0..1023
#pragma unroll
    for (int mi = 0; mi < 4; ++mi) {
      const int m0 = bm * 128 + wm * 64 + mi * 16 + quad * 4;   // n, r-contig
      const int bh0 = (m0 >> 11) * HEADS;
      const int n0 = m0 & 2047;
#pragma unroll
      for (int ni = 0; ni < 4; ++ni) {
        const int vcol = colbase + ni * 16 + l15;
        const int h = vcol >> 6, dd = vcol & 63;
        *(u16x4*)&vtb[((bh0 + h) * DHEAD + dd) * NSEQ + n0] = cvt4(acc[mi][ni]);
      }
    }
  }
}

// ---------------- flash attention, transposed-S, fixed-offset softmax.
// R16: block = (bh, 64-row q tile), 512 threads / 8 waves, grid 1024,
// LDS 42.2KB -> 3 blocks/CU = 6 waves/SIMD. wave = (ikv = wave>>2 kv-half,
// jq = wave&3 16-q slice). Per wave per iter: 2 gl_lds16 staging, ak 4 +
// av 4 frag reads, 4 QK MFMA, 8 exp2, 2 P writes, 1 bp read, 4 PV MFMA.
// Double-buffered K/V, ONE barrier per kv-iter. p = exp2(s-32).
// Epilogue: 2-way cross-wave (ikv) O/lsum reduction in dead K/V LDS.
__global__ __launch_bounds__(512, 6) void attn_kernel(
    const unsigned short* __restrict__ qb, const unsigned short* __restrict__ kb,
    const unsigned short* __restrict__ vtb, unsigned short* __restrict__ attn_out) {
  __shared__ __attribute__((aligned(16))) unsigned short KVs[4][64 * 64]; // K0,K1,Vt0,Vt1 (swizzled)
  __shared__ __attribute__((aligned(16))) unsigned short Ps[8][16][36];   // per-wave P slice
  __shared__ float Lred[4][16];
  const int tid = threadIdx.x, wave = tid >> 6, lane = tid & 63;
  const int l15 = lane & 15, quad = lane >> 4;
  const int bh = blockIdx.x, qt = blockIdx.y;
  const int b = bh >> 4, h = bh & 15;
  const int jq = wave & 3;    // q 16-row slice
  const int ikv = wave >> 2;  // kv-half (32 rows of the 64-tile)
  const int qbase = qt * 64 + jq * 16;

  // Q fragments for this wave's 16 q rows (B-operand: n=l15=q, k=quad*8+e)
  bf16x8 aq[2];
  {
    const unsigned short* qrow = qb + (bh * NSEQ + qbase + l15) * DHEAD;
    aq[0] = as_bf(*(const u16x8*)(qrow + quad * 8));
    aq[1] = as_bf(*(const u16x8*)(qrow + 32 + quad * 8));
  }

  float lsum = 0.f;
  f32x4 occ[4] = {};   // partial O^T: [ct: d=ct*16+quad*4+r], q=l15

  // staging: each of 8 waves stages 8 rows (1 gl_lds16) of K and of Vt
  const int lrow = lane >> 3;
  const int gcol = ((lane & 7) ^ lrow) << 3;
  const unsigned short* Kb = kb  + (bh * NSEQ + wave * 8 + lrow) * DHEAD + gcol;
  const unsigned short* Vb = vtb + (bh * DHEAD + wave * 8 + lrow) * NSEQ + gcol;

  // prologue: stage kv tile 0 into buffer 0 (K -> KVs[0], Vt -> KVs[2])
  gl_lds16(Kb, &KVs[0][(wave * 8) * 64]);
  gl_lds16(Vb, &KVs[2][(wave * 8) * 64]);

  // diagonal: q = qt*64 + jq*16 + l15, kv = it*64 + ikv*32 + mt*16 + quad*4+r.
  // Hit iff it == qt, ikv == jq>>1, mt == jq&1, quad*4+r == l15.
  const int diag_it = qt;
  const bool diag_wave = (ikv == (jq >> 1));
  const int diag_mt = jq & 1;

  for (int it = 0; it < NSEQ / 64; ++it) {
    const int cur = it & 1;
    __syncthreads();   // drains this wave's async loads into buf[cur]
    if (it < NSEQ / 64 - 1) {
      gl_lds16(Kb + (it + 1) * 64 * DHEAD, &KVs[cur ^ 1][(wave * 8) * 64]);
      gl_lds16(Vb + (it + 1) * 64,         &KVs[2 + (cur ^ 1)][(wave * 8) * 64]);
    }
    // fragments: only this wave's kv-half
    bf16x8 ak[2][2];   // [kk][mt]: K rows ikv*32+mt*16+l15, d chunk kk*4+quad
#pragma unroll
    for (int kk = 0; kk < 2; ++kk)
#pragma unroll
      for (int mt = 0; mt < 2; ++mt)
        ak[kk][mt] = lds_frag(&KVs[cur][0], ikv * 32 + mt * 16 + l15, kk * 4 + quad);
    bf16x8 av[4];      // [ct]: Vt rows d=ct*16+l15, kv chunk ikv*4+quad
#pragma unroll
    for (int ct = 0; ct < 4; ++ct)
      av[ct] = lds_frag(&KVs[2 + cur][0], ct * 16 + l15, ikv * 4 + quad);

    // ---- QK^T: S^T slice 32kv x 16q, 4 MFMA ----
    f32x4 scc[2];
#pragma unroll
    for (int mt = 0; mt < 2; ++mt) scc[mt] = (f32x4){-32.f, -32.f, -32.f, -32.f};
    __builtin_amdgcn_s_setprio(1);
#pragma unroll
    for (int kk = 0; kk < 2; ++kk)
#pragma unroll
      for (int mt = 0; mt < 2; ++mt)
        scc[mt] = __builtin_amdgcn_mfma_f32_16x16x32_bf16(ak[kk][mt], aq[kk], scc[mt], 0, 0, 0);
    __builtin_amdgcn_s_setprio(0);

#pragma unroll
    for (int mt = 0; mt < 2; ++mt)
#pragma unroll
      for (int r = 0; r < 4; ++r) scc[mt][r] = EXP2(scc[mt][r]);

    // diagonal mask (wave-uniform branch; zero BEFORE summing)
    if (it == diag_it && diag_wave) {
#pragma unroll
      for (int r = 0; r < 4; ++r)
        if (quad * 4 + r == l15) scc[diag_mt][r] = 0.f;
    }

    {
      f32x4 t = scc[0] + scc[1];
      lsum += (t[0] + t[1]) + (t[2] + t[3]);
    }

    // ---- P -> LDS (wave-private slice, same-wave in-order) ----
    // row q (0..15) = l15, col kv (0..31) = mt*16+quad*4
#pragma unroll
    for (int mt = 0; mt < 2; ++mt)
      *(u16x4*)&Ps[wave][l15][mt * 16 + quad * 4] = cvt4(scc[mt]);

    bf16x8 bp = as_bf(*(const u16x8*)&Ps[wave][l15][quad * 8]);

    // ---- PV: partial O^T over this kv-half, 4 MFMA (K=32) ----
    __builtin_amdgcn_s_setprio(1);
#pragma unroll
    for (int ct = 0; ct < 4; ++ct)
      occ[ct] = __builtin_amdgcn_mfma_f32_16x16x32_bf16(av[ct], bp, occ[ct], 0, 0, 0);
    __builtin_amdgcn_s_setprio(0);
  }

  // within-wave lsum reduction over quads (kv sub-slices)
  lsum += __shfl_xor(lsum, 16);
  lsum += __shfl_xor(lsum, 32);

  // ---- 2-way cross-wave reduction: ikv=1 partials added into ikv=0 ----
  __syncthreads();                       // all compute done; K/V LDS dead
  float* Ored = (float*)&KVs[0][0];      // 16 KB overlay: 4 KB per jq
  if (ikv == 1) {
#pragma unroll
    for (int ct = 0; ct < 4; ++ct)
      *(f32x4*)&Ored[((jq * 4 + ct) * 64 + lane) * 4] = occ[ct];
    if (quad == 0) Lred[jq][l15] = lsum;
  }
  __syncthreads();
  if (ikv == 0) {
#pragma unroll
    for (int ct = 0; ct < 4; ++ct)
      occ[ct] += *(const f32x4*)&Ored[((jq * 4 + ct) * 64 + lane) * 4];
    const float l = lsum + Lred[jq][l15];
    const float rl = __builtin_amdgcn_rcpf(l);
    const int qg = qbase + l15;
#pragma unroll
    for (int ct = 0; ct < 4; ++ct) {
      f32x4 ov = occ[ct] * rl;
      *(u16x4*)&attn_out[(b * NSEQ + qg) * DIMM + h * DHEAD + ct * 16 + quad * 4] = cvt4(ov);
    }
  }
}

// ---------------- output projection (C^T): [4096,1024] @ woutT[1024,1024] -> fp32
// M64 x N128 tiles, BK=128 (8 K-iters, 32 MFMA/wave/barrier), single-buffer
// 48KB LDS, grid (8,64)=512 = 2 blocks/CU exact.
__global__ __launch_bounds__(256, 2) void gemm_out_kernel(
    const unsigned short* __restrict__ A,   // attn bf16 [4096,1024]
    const unsigned short* __restrict__ Bt,  // woutT bf16 [1024,1024]
    float* __restrict__ out) {
  __shared__ __attribute__((aligned(16))) unsigned short As[64 * 128];   // 16 KB
  __shared__ __attribute__((aligned(16))) unsigned short Bs[128 * 128];  // 32 KB
  const int tid = threadIdx.x;
  const int bm = blockIdx.y, bn = blockIdx.x;
  const int lane = tid & 63, wave = tid >> 6;
  const int l15 = lane & 15, quad = lane >> 4;
  const int wm = wave >> 1, wn = wave & 1;
  // staging lane mapping for 256B rows: 4 rows per gl_lds16
  const int rl4 = lane >> 4;   // row within instr, 0..3
  const int cp  = lane & 15;   // chunk position, 0..15
  const int cx  = cp ^ rl4;    // base xor (LDS[row][p] = G[row][p ^ (row&15)])
  const int Arow0 = bm * 64 + wave * 16 + rl4;
  const int Brow0 = bn * 128 + wave * 32 + rl4;
  f32x4 acc[2][4] = {};

  for (int it = 0; it < 8; ++it) {
    const int k0 = it * 128;
    // stage A: 64 rows x 128k (4 instrs/wave), B: 128 rows (8 instrs/wave)
#pragma unroll
    for (int j = 0; j < 4; ++j)
      gl_lds16(A + (Arow0 + j * 4) * DIMM + k0 + ((cx ^ (j << 2)) << 3),
               &As[(wave * 16 + j * 4) * 128]);
#pragma unroll
    for (int j = 0; j < 8; ++j)
      gl_lds16(Bt + (Brow0 + j * 4) * DIMM + k0 + ((cx ^ ((j & 3) << 2)) << 3),
               &Bs[(wave * 32 + j * 4) * 128]);
    __syncthreads();
#pragma unroll
    for (int kk = 0; kk < 4; ++kk) {
      bf16x8 af[2], bfr[4];
#pragma unroll
      for (int mi = 0; mi < 2; ++mi) af[mi]  = lds_frag128(As, wm * 32 + mi * 16 + l15, kk * 4 + quad);
#pragma unroll
      for (int ni = 0; ni < 4; ++ni) bfr[ni] = lds_frag128(Bs, wn * 64 + ni * 16 + l15, kk * 4 + quad);
#pragma unroll
      for (int mi = 0; mi < 2; ++mi)
#pragma unroll
        for (int ni = 0; ni < 4; ++ni)
          acc[mi][ni] = __builtin_amdgcn_mfma_f32_16x16x32_bf16(bfr[ni], af[mi], acc[mi][ni], 0, 0, 0);
    }
    __syncthreads();
  }
  // C^T epilogue: col=l15 -> out row m; row(quad*4+r, r-contig) -> out col.
#pragma unroll
  for (int mi = 0; mi < 2; ++mi) {
    const int m = bm * 64 + wm * 32 + mi * 16 + l15;   // attn row
#pragma unroll
    for (int ni = 0; ni < 4; ++ni) {
      const int col = bn * 128 + wn * 64 + ni * 16 + quad * 4;  // r-contig
      *(f32x4*)&out[m * DIMM + col] = acc[mi][ni];
    }
  }
}

extern "C" void kernel_launch(void* const* d_in, const int* in_sizes, int n_in,
                              void* d_out, int out_size, void* d_ws, size_t ws_size,
                              hipStream_t stream) {
  const float* x     = (const float*)d_in[0];
  const float* gamma = (const float*)d_in[1];
  const float* beta  = (const float*)d_in[2];
  const float* w_qkv = (const float*)d_in[3];  // [1024, 3072]
  const float* w_out = (const float*)d_in[4];  // [1024, 1024]
  float* out = (float*)d_out;

  char* ws = (char*)d_ws;
  unsigned short* xn    = (unsigned short*)(ws);                        // 8 MB
  unsigned short* wqkvT = (unsigned short*)(ws + 8388608);              // 6 MB
  unsigned short* woutT = (unsigned short*)(ws + 14680064);             // 2 MB
  unsigned short* qbuf  = (unsigned short*)(ws + 16777216);             // 8 MB
  unsigned short* kbuf  = (unsigned short*)(ws + 25165824);             // 8 MB
  unsigned short* vtbuf = (unsigned short*)(ws + 33554432);             // 8 MB
  unsigned short* attnb = (unsigned short*)(ws + 41943040);             // 8 MB

  prep_kernel<<<MROWS + (QKVN + DIMM) / 32 * (DIMM / 32), 256, 0, stream>>>(
      x, gamma, beta, w_qkv, w_out, xn, wqkvT, woutT);
  gemm_qkv_kernel<<<dim3(24, MROWS / 128), 256, 0, stream>>>(xn, wqkvT, qbuf, kbuf, vtbuf);
  attn_kernel<<<dim3(BATCH * HEADS, NSEQ / 64), 512, 0, stream>>>(qbuf, kbuf, vtbuf, attnb);
  gemm_out_kernel<<<dim3(DIMM / 128, MROWS / 64), 256, 0, stream>>>(attnb, woutT, out);
}

// Round 7
// 180.630 us; speedup vs baseline: 1.0794x; 1.0794x over previous
//
#include <hip/hip_runtime.h>

// Fused: LayerNorm -> QKV proj -> per-head attention (diag masked) -> out proj
// B=2, N=2048, D=1024, H=16, dh=64. bf16 MFMA 16x16x32 everywhere.
// R17: (1) attn reverted to R15 exactly (48.5us best; R16's 64-q blocks
//     doubled staging/barriers and caused partial-line write amplification,
//     63.7us). (2) gemm_out re-tiled M64xN128 -> M64xN64, BK=128: LDS 48->32
//     KB, grid 512 -> 1024 = 4 blocks/CU = 4 waves/SIMD (was 2 -- the same
//     latency-bound config R15 proved costly in attn). B re-reads L2-served.

#define DIMM   1024
#define NSEQ   2048
#define BATCH  2
#define HEADS  16
#define DHEAD  64
#define QKVN   3072
#define MROWS  4096   // BATCH*NSEQ

typedef float          f32x4  __attribute__((ext_vector_type(4)));
typedef __bf16         bf16x8 __attribute__((ext_vector_type(8)));
typedef __bf16         bf16x4 __attribute__((ext_vector_type(4)));
typedef unsigned short u16x8  __attribute__((ext_vector_type(8)));
typedef unsigned short u16x4  __attribute__((ext_vector_type(4)));

// SCALE * log2(e): fold into q so softmax uses exp2 directly.
#define QSCALE (0.125f * 1.4426950408889634f)

#if __has_builtin(__builtin_amdgcn_exp2f)
#define EXP2(x) __builtin_amdgcn_exp2f(x)
#else
#define EXP2(x) exp2f(x)
#endif

__device__ __forceinline__ unsigned short f2bf(float f) {
  unsigned u = __builtin_bit_cast(unsigned, f);
  u += 0x7FFFu + ((u >> 16) & 1u);   // round-to-nearest-even
  return (unsigned short)(u >> 16);
}
__device__ __forceinline__ bf16x8 as_bf(u16x8 v) { return __builtin_bit_cast(bf16x8, v); }

// f32x4 -> 4 bf16 (RNE)
__device__ __forceinline__ u16x4 cvt4(f32x4 v) {
  bf16x4 b;
  b[0] = (__bf16)v[0]; b[1] = (__bf16)v[1]; b[2] = (__bf16)v[2]; b[3] = (__bf16)v[3];
  return __builtin_bit_cast(u16x4, b);
}

// async global->LDS, 16B per lane; LDS dest = wave-uniform base + lane*16
__device__ __forceinline__ void gl_lds16(const unsigned short* g, unsigned short* l) {
  __builtin_amdgcn_global_load_lds(
      (const __attribute__((address_space(1))) unsigned*)g,
      (__attribute__((address_space(3))) unsigned*)l, 16, 0, 0);
}

// swizzled b128 fragment read from an unpadded [rows][64] bf16 tile:
// LDS chunk c at row r holds global chunk c ^ (r&7).
__device__ __forceinline__ bf16x8 lds_frag(const unsigned short* base, int row, int chunk) {
  return as_bf(*(const u16x8*)&base[row * 64 + ((chunk ^ (row & 7)) << 3)]);
}

// same for [rows][128] bf16 tiles (16 chunks/row, 4-bit xor)
__device__ __forceinline__ bf16x8 lds_frag128(const unsigned short* base, int row, int chunk) {
  return as_bf(*(const u16x8*)&base[row * 128 + ((chunk ^ (row & 15)) << 3)]);
}

// ---------------- weight transpose tile + fp32->bf16: dst[c][r] = src[r][c]
__device__ __forceinline__ void transpose_tile(
    const float* __restrict__ src, unsigned short* __restrict__ dst,
    int R, int C, int bx, int by, int tid) {
  __shared__ float t[32][33];
  const int rb = by * 32, cb = bx * 32;
  const int r0 = tid >> 5;   // 0..7
  const int c  = tid & 31;
#pragma unroll
  for (int i = 0; i < 4; ++i)
    t[r0 + i * 8][c] = src[(rb + r0 + i * 8) * C + cb + c];
  __syncthreads();
#pragma unroll
  for (int i = 0; i < 4; ++i)
    dst[(cb + r0 + i * 8) * R + rb + c] = f2bf(t[c][r0 + i * 8]);
}

// ---------------- prep: LN (blocks 0..4095) + weight transposes (4096..8191)
__global__ __launch_bounds__(256) void prep_kernel(
    const float* __restrict__ x, const float* __restrict__ g,
    const float* __restrict__ be, const float* __restrict__ w_qkv,
    const float* __restrict__ w_out, unsigned short* __restrict__ xn,
    unsigned short* __restrict__ wqkvT, unsigned short* __restrict__ woutT) {
  const int bid = blockIdx.x, tid = threadIdx.x;
  if (bid < MROWS) {
    // LayerNorm: one row (1024) per 256-thread block, bf16 out
    const int row = bid;
    const int wave = tid >> 6, lane = tid & 63;
    const float4 v = *(const float4*)&x[row * DIMM + tid * 4];
    float s  = v.x + v.y + v.z + v.w;
    float s2 = v.x * v.x + v.y * v.y + v.z * v.z + v.w * v.w;
#pragma unroll
    for (int o = 32; o >= 1; o >>= 1) { s += __shfl_xor(s, o); s2 += __shfl_xor(s2, o); }
    __shared__ float ps[4], ps2[4];
    if (lane == 0) { ps[wave] = s; ps2[wave] = s2; }
    __syncthreads();
    s  = ps[0] + ps[1] + ps[2] + ps[3];
    s2 = ps2[0] + ps2[1] + ps2[2] + ps2[3];
    const float mu  = s * (1.0f / DIMM);
    const float var = s2 * (1.0f / DIMM) - mu * mu;
    const float rs  = rsqrtf(var + 1e-5f);
    const float4 gg = *(const float4*)&g[tid * 4];
    const float4 bb = *(const float4*)&be[tid * 4];
    u16x4 o;
    o[0] = f2bf((v.x - mu) * rs * gg.x + bb.x);
    o[1] = f2bf((v.y - mu) * rs * gg.y + bb.y);
    o[2] = f2bf((v.z - mu) * rs * gg.z + bb.z);
    o[3] = f2bf((v.w - mu) * rs * gg.w + bb.w);
    *(u16x4*)&xn[row * DIMM + tid * 4] = o;
  } else {
    const int t = bid - MROWS;            // 0..4095
    const int bx = t & 127, by = t >> 7;  // 128 x 32
    if (bx < QKVN / 32) transpose_tile(w_qkv, wqkvT, DIMM, QKVN, bx, by, tid);
    else                transpose_tile(w_out, woutT, DIMM, DIMM, bx - QKVN / 32, by, tid);
  }
}

// ---------------- merged QKV GEMM: 128x128 tiles, single-buffer 32KB LDS,
// 3 blocks/CU co-resident (grid 768). bn 0..15 -> q/k (C^T), 16..23 -> v (C).
__global__ __launch_bounds__(256, 3) void gemm_qkv_kernel(
    const unsigned short* __restrict__ A, const unsigned short* __restrict__ Bt,
    unsigned short* __restrict__ qb, unsigned short* __restrict__ kb,
    unsigned short* __restrict__ vtb) {
  __shared__ __attribute__((aligned(16))) unsigned short As[128 * 64];  // 16 KB
  __shared__ __attribute__((aligned(16))) unsigned short Bs[128 * 64];  // 16 KB
  const int tid = threadIdx.x;
  const int bm = blockIdx.y, bn = blockIdx.x;
  const int lane = tid & 63, wave = tid >> 6;
  const int l15 = lane & 15, quad = lane >> 4;
  const int wm = wave >> 1, wn = wave & 1;
  const int lrow = lane >> 3;
  const int gcol = ((lane & 7) ^ lrow) << 3;
  const unsigned short* Ab = A  + (bm * 128 + wave * 32 + lrow) * DIMM + gcol;
  const unsigned short* Bb = Bt + (bn * 128 + wave * 32 + lrow) * DIMM + gcol;
  const bool swap = (bn < 16);
  f32x4 acc[4][4] = {};

  for (int k0 = 0; k0 < DIMM; k0 += 64) {
#pragma unroll
    for (int j = 0; j < 4; ++j) {
      gl_lds16(Ab + j * 8 * DIMM + k0, &As[(wave * 32 + j * 8) * 64]);
      gl_lds16(Bb + j * 8 * DIMM + k0, &Bs[(wave * 32 + j * 8) * 64]);
    }
    __syncthreads();
#pragma unroll
    for (int kk = 0; kk < 2; ++kk) {
      bf16x8 af[4], bfr[4];
#pragma unroll
      for (int mi = 0; mi < 4; ++mi) af[mi]  = lds_frag(As, wm * 64 + mi * 16 + l15, kk * 4 + quad);
#pragma unroll
      for (int ni = 0; ni < 4; ++ni) bfr[ni] = lds_frag(Bs, wn * 64 + ni * 16 + l15, kk * 4 + quad);
      if (swap) {
#pragma unroll
        for (int mi = 0; mi < 4; ++mi)
#pragma unroll
          for (int ni = 0; ni < 4; ++ni)
            acc[mi][ni] = __builtin_amdgcn_mfma_f32_16x16x32_bf16(bfr[ni], af[mi], acc[mi][ni], 0, 0, 0);
      } else {
#pragma unroll
        for (int mi = 0; mi < 4; ++mi)
#pragma unroll
          for (int ni = 0; ni < 4; ++ni)
            acc[mi][ni] = __builtin_amdgcn_mfma_f32_16x16x32_bf16(af[mi], bfr[ni], acc[mi][ni], 0, 0, 0);
      }
    }
    __syncthreads();
  }

  if (swap) {
    // q/k blocks: C^T -> reg r runs along weight col (dd) -> b64 stores.
    const int colbase = bn * 128 + wn * 64;        // wave-uniform
    const int which = colbase >> 10;               // 0=q, 1=k
    unsigned short* dst = which ? kb : qb;
    const float sc = which ? 1.0f : QSCALE;
#pragma unroll
    for (int mi = 0; mi < 4; ++mi) {
      const int m = bm * 128 + wm * 64 + mi * 16 + l15;   // xn row
      const int bh0 = (m >> 11) * HEADS;
      const int n = m & 2047;
#pragma unroll
      for (int ni = 0; ni < 4; ++ni) {
        const int wc = (colbase & 1023) + ni * 16 + quad * 4;  // r-contig
        const int h = wc >> 6, dd = wc & 63;
        f32x4 v = acc[mi][ni] * sc;
        *(u16x4*)&dst[((bh0 + h) * NSEQ + n) * DHEAD + dd] = cvt4(v);
      }
    }
  } else {
    // v blocks: C -> reg r runs along n -> b64 stores to vt.
    const int colbase = bn * 128 + wn * 64 - 2048;   // v col base, 0..1023
#pragma unroll
    for (int mi = 0; mi < 4; ++mi) {
      const int m0 = bm * 128 + wm * 64 + mi * 16 + quad * 4;   // n, r-contig
      const int bh0 = (m0 >> 11) * HEADS;
      const int n0 = m0 & 2047;
#pragma unroll
      for (int ni = 0; ni < 4; ++ni) {
        const int vcol = colbase + ni * 16 + l15;
        const int h = vcol >> 6, dd = vcol & 63;
        *(u16x4*)&vtb[((bh0 + h) * DHEAD + dd) * NSEQ + n0] = cvt4(acc[mi][ni]);
      }
    }
  }
}

// ---------------- flash attention, transposed-S, fixed-offset softmax.
// R15 (best known, 48.5us): block = (bh, 128-row q tile), 512 threads /
// 8 waves, 2 blocks/CU -> 4 waves/SIMD. wave = (ikv = wave>>2, jq = wave&3):
// 32 kv x 32 q slice. Double-buffered K/V, ONE barrier per kv-iter.
// p = exp2(s-32); scale cancels. Epilogue: 2-way cross-wave (ikv) O/lsum
// reduction in dead K/V LDS.
__global__ __launch_bounds__(512, 4) void attn_kernel(
    const unsigned short* __restrict__ qb, const unsigned short* __restrict__ kb,
    const unsigned short* __restrict__ vtb, unsigned short* __restrict__ attn_out) {
  __shared__ __attribute__((aligned(16))) unsigned short KVs[4][64 * 64]; // K0,K1,Vt0,Vt1 (swizzled)
  __shared__ __attribute__((aligned(16))) unsigned short Ps[8][32][36];   // per-wave P slice
  __shared__ float Lred[4][2][16];
  const int tid = threadIdx.x, wave = tid >> 6, lane = tid & 63;
  const int l15 = lane & 15, quad = lane >> 4;
  const int bh = blockIdx.x, qt = blockIdx.y;
  const int b = bh >> 4, h = bh & 15;
  const int jq = wave & 3;    // q 32-row slice
  const int ikv = wave >> 2;  // kv-half (32 rows of the 64-tile)
  const int qbase = qt * 128 + jq * 32;

  // Q fragments for this wave's 32 q rows (B-operand: n=l15=q, k=quad*8+e)
  bf16x8 aq[2][2];
#pragma unroll
  for (int nt = 0; nt < 2; ++nt) {
    const unsigned short* qrow = qb + (bh * NSEQ + qbase + nt * 16 + l15) * DHEAD;
    aq[nt][0] = as_bf(*(const u16x8*)(qrow + quad * 8));
    aq[nt][1] = as_bf(*(const u16x8*)(qrow + 32 + quad * 8));
  }

  float lsum[2] = {0.f, 0.f};
  f32x4 occ[4][2] = {};   // partial O^T: [ct: d=ct*16+quad*4+r][nt: q=nt*16+l15]

  // staging: each of 8 waves stages 8 rows (1 gl_lds16) of K and of Vt
  const int lrow = lane >> 3;
  const int gcol = ((lane & 7) ^ lrow) << 3;
  const unsigned short* Kb = kb  + (bh * NSEQ + wave * 8 + lrow) * DHEAD + gcol;
  const unsigned short* Vb = vtb + (bh * DHEAD + wave * 8 + lrow) * NSEQ + gcol;

  // prologue: stage kv tile 0 into buffer 0 (K -> KVs[0], Vt -> KVs[2])
  gl_lds16(Kb, &KVs[0][(wave * 8) * 64]);
  gl_lds16(Vb, &KVs[2][(wave * 8) * 64]);

  // diagonal: global q == global kv. q = qt*128 + jq*32 + nt*16 + l15,
  // kv = it*64 + ikv*32 + mt*16 + quad*4 + r. Hit iff it == qt*2 + (jq>>1),
  // ikv == (jq&1), mt == nt, quad*4+r == l15.
  const int diag_it = qt * 2 + (jq >> 1);
  const bool diag_wave = (ikv == (jq & 1));

  for (int it = 0; it < NSEQ / 64; ++it) {
    const int cur = it & 1;
    __syncthreads();   // drains this wave's async loads into buf[cur]
    if (it < NSEQ / 64 - 1) {
      gl_lds16(Kb + (it + 1) * 64 * DHEAD, &KVs[cur ^ 1][(wave * 8) * 64]);
      gl_lds16(Vb + (it + 1) * 64,         &KVs[2 + (cur ^ 1)][(wave * 8) * 64]);
    }
    // fragments: only this wave's kv-half
    bf16x8 ak[2][2];   // [kk][mt]: K rows ikv*32+mt*16+l15, d chunk kk*4+quad
#pragma unroll
    for (int kk = 0; kk < 2; ++kk)
#pragma unroll
      for (int mt = 0; mt < 2; ++mt)
        ak[kk][mt] = lds_frag(&KVs[cur][0], ikv * 32 + mt * 16 + l15, kk * 4 + quad);
    bf16x8 av[4];      // [ct]: Vt rows d=ct*16+l15, kv chunk ikv*4+quad
#pragma unroll
    for (int ct = 0; ct < 4; ++ct)
      av[ct] = lds_frag(&KVs[2 + cur][0], ct * 16 + l15, ikv * 4 + quad);

    // ---- QK^T: S^T slice 32kv x 32q, 8 MFMA ----
    f32x4 scc[2][2];
#pragma unroll
    for (int mt = 0; mt < 2; ++mt)
#pragma unroll
      for (int nt = 0; nt < 2; ++nt) scc[mt][nt] = (f32x4){-32.f, -32.f, -32.f, -32.f};
    __builtin_amdgcn_s_setprio(1);
#pragma unroll
    for (int kk = 0; kk < 2; ++kk)
#pragma unroll
      for (int mt = 0; mt < 2; ++mt)
#pragma unroll
        for (int nt = 0; nt < 2; ++nt)
          scc[mt][nt] = __builtin_amdgcn_mfma_f32_16x16x32_bf16(ak[kk][mt], aq[nt][kk], scc[mt][nt], 0, 0, 0);
    __builtin_amdgcn_s_setprio(0);

#pragma unroll
    for (int mt = 0; mt < 2; ++mt)
#pragma unroll
      for (int nt = 0; nt < 2; ++nt)
#pragma unroll
        for (int r = 0; r < 4; ++r) scc[mt][nt][r] = EXP2(scc[mt][nt][r]);

    // diagonal mask (wave-uniform branch; zero BEFORE summing)
    if (it == diag_it && diag_wave) {
#pragma unroll
      for (int nt = 0; nt < 2; ++nt)
#pragma unroll
        for (int r = 0; r < 4; ++r)
          if (quad * 4 + r == l15) scc[nt][nt][r] = 0.f;
    }

#pragma unroll
    for (int nt = 0; nt < 2; ++nt) {
      f32x4 t = scc[0][nt] + scc[1][nt];
      lsum[nt] += (t[0] + t[1]) + (t[2] + t[3]);
    }

    // ---- P -> LDS (wave-private slice, same-wave in-order) ----
    // row q (0..31) = nt*16+l15, col kv (0..31) = mt*16+quad*4
#pragma unroll
    for (int mt = 0; mt < 2; ++mt)
#pragma unroll
      for (int nt = 0; nt < 2; ++nt)
        *(u16x4*)&Ps[wave][nt * 16 + l15][mt * 16 + quad * 4] = cvt4(scc[mt][nt]);

    bf16x8 bp[2];
#pragma unroll
    for (int nt = 0; nt < 2; ++nt)
      bp[nt] = as_bf(*(const u16x8*)&Ps[wave][nt * 16 + l15][quad * 8]);

    // ---- PV: partial O^T over this kv-half, 8 MFMA (K=32) ----
    __builtin_amdgcn_s_setprio(1);
#pragma unroll
    for (int ct = 0; ct < 4; ++ct)
#pragma unroll
      for (int nt = 0; nt < 2; ++nt)
        occ[ct][nt] = __builtin_amdgcn_mfma_f32_16x16x32_bf16(av[ct], bp[nt], occ[ct][nt], 0, 0, 0);
    __builtin_amdgcn_s_setprio(0);
  }

  // within-wave lsum reduction over quads (kv sub-slices)
#pragma unroll
  for (int nt = 0; nt < 2; ++nt) {
    lsum[nt] += __shfl_xor(lsum[nt], 16);
    lsum[nt] += __shfl_xor(lsum[nt], 32);
  }

  // ---- 2-way cross-wave reduction: ikv=1 partials added into ikv=0 ----
  __syncthreads();                       // all compute done; K/V LDS dead
  float* Ored = (float*)&KVs[0][0];      // 32 KB overlay: 8 KB per jq
  if (ikv == 1) {
#pragma unroll
    for (int ct = 0; ct < 4; ++ct)
#pragma unroll
      for (int nt = 0; nt < 2; ++nt)
        *(f32x4*)&Ored[((jq * 8 + ct * 2 + nt) * 64 + lane) * 4] = occ[ct][nt];
    if (quad == 0) {
#pragma unroll
      for (int nt = 0; nt < 2; ++nt) Lred[jq][nt][l15] = lsum[nt];
    }
  }
  __syncthreads();
  if (ikv == 0) {
#pragma unroll
    for (int ct = 0; ct < 4; ++ct)
#pragma unroll
      for (int nt = 0; nt < 2; ++nt)
        occ[ct][nt] += *(const f32x4*)&Ored[((jq * 8 + ct * 2 + nt) * 64 + lane) * 4];
#pragma unroll
    for (int nt = 0; nt < 2; ++nt) {
      const float l = lsum[nt] + Lred[jq][nt][l15];
      const float rl = __builtin_amdgcn_rcpf(l);
      const int qg = qbase + nt * 16 + l15;
#pragma unroll
      for (int ct = 0; ct < 4; ++ct) {
        f32x4 ov = occ[ct][nt] * rl;
        *(u16x4*)&attn_out[(b * NSEQ + qg) * DIMM + h * DHEAD + ct * 16 + quad * 4] = cvt4(ov);
      }
    }
  }
}

// ---------------- output projection (C^T): [4096,1024] @ woutT[1024,1024] -> fp32
// R17: M64 x N64 tiles, BK=128 (8 K-iters), 32KB LDS, grid (16,64)=1024 =
// 4 blocks/CU = 16 waves/CU = 4 waves/SIMD (was 2 -- latency-bound).
__global__ __launch_bounds__(256, 4) void gemm_out_kernel(
    const unsigned short* __restrict__ A,   // attn bf16 [4096,1024]
    const unsigned short* __restrict__ Bt,  // woutT bf16 [1024,1024]
    float* __restrict__ out) {
  __shared__ __attribute__((aligned(16))) unsigned short As[64 * 128];   // 16 KB
  __shared__ __attribute__((aligned(16))) unsigned short Bs[64 * 128];   // 16 KB
  const int tid = threadIdx.x;
  const int bm = blockIdx.y, bn = blockIdx.x;
  const int lane = tid & 63, wave = tid >> 6;
  const int l15 = lane & 15, quad = lane >> 4;
  const int wm = wave >> 1, wn = wave & 1;
  // staging lane mapping for 256B rows: 4 rows per gl_lds16
  const int rl4 = lane >> 4;   // row within instr, 0..3
  const int cp  = lane & 15;   // chunk position, 0..15
  const int cx  = cp ^ rl4;    // base xor (LDS[row][p] = G[row][p ^ (row&15)])
  const int Arow0 = bm * 64 + wave * 16 + rl4;
  const int Brow0 = bn * 64 + wave * 16 + rl4;
  f32x4 acc[2][2] = {};

  for (int it = 0; it < 8; ++it) {
    const int k0 = it * 128;
    // stage A: 64 rows x 128k (4 instrs/wave), B: 64 rows (4 instrs/wave)
#pragma unroll
    for (int j = 0; j < 4; ++j)
      gl_lds16(A + (Arow0 + j * 4) * DIMM + k0 + ((cx ^ (j << 2)) << 3),
               &As[(wave * 16 + j * 4) * 128]);
#pragma unroll
    for (int j = 0; j < 4; ++j)
      gl_lds16(Bt + (Brow0 + j * 4) * DIMM + k0 + ((cx ^ (j << 2)) << 3),
               &Bs[(wave * 16 + j * 4) * 128]);
    __syncthreads();
#pragma unroll
    for (int kk = 0; kk < 4; ++kk) {
      bf16x8 af[2], bfr[2];
#pragma unroll
      for (int mi = 0; mi < 2; ++mi) af[mi]  = lds_frag128(As, wm * 32 + mi * 16 + l15, kk * 4 + quad);
#pragma unroll
      for (int ni = 0; ni < 2; ++ni) bfr[ni] = lds_frag128(Bs, wn * 32 + ni * 16 + l15, kk * 4 + quad);
#pragma unroll
      for (int mi = 0; mi < 2; ++mi)
#pragma unroll
        for (int ni = 0; ni < 2; ++ni)
          acc[mi][ni] = __builtin_amdgcn_mfma_f32_16x16x32_bf16(bfr[ni], af[mi], acc[mi][ni], 0, 0, 0);
    }
    __syncthreads();
  }
  // C^T epilogue: col=l15 -> out row m; row(quad*4+r, r-contig) -> out col.
#pragma unroll
  for (int mi = 0; mi < 2; ++mi) {
    const int m = bm * 64 + wm * 32 + mi * 16 + l15;   // attn row
#pragma unroll
    for (int ni = 0; ni < 2; ++ni) {
      const int col = bn * 64 + wn * 32 + ni * 16 + quad * 4;  // r-contig
      *(f32x4*)&out[m * DIMM + col] = acc[mi][ni];
    }
  }
}

extern "C" void kernel_launch(void* const* d_in, const int* in_sizes, int n_in,
                              void* d_out, int out_size, void* d_ws, size_t ws_size,
                              hipStream_t stream) {
  const float* x     = (const float*)d_in[0];
  const float* gamma = (const float*)d_in[1];
  const float* beta  = (const float*)d_in[2];
  const float* w_qkv = (const float*)d_in[3];  // [1024, 3072]
  const float* w_out = (const float*)d_in[4];  // [1024, 1024]
  float* out = (float*)d_out;

  char* ws = (char*)d_ws;
  unsigned short* xn    = (unsigned short*)(ws);                        // 8 MB
  unsigned short* wqkvT = (unsigned short*)(ws + 8388608);              // 6 MB
  unsigned short* woutT = (unsigned short*)(ws + 14680064);             // 2 MB
  unsigned short* qbuf  = (unsigned short*)(ws + 16777216);             // 8 MB
  unsigned short* kbuf  = (unsigned short*)(ws + 25165824);             // 8 MB
  unsigned short* vtbuf = (unsigned short*)(ws + 33554432);             // 8 MB
  unsigned short* attnb = (unsigned short*)(ws + 41943040);             // 8 MB

  prep_kernel<<<MROWS + (QKVN + DIMM) / 32 * (DIMM / 32), 256, 0, stream>>>(
      x, gamma, beta, w_qkv, w_out, xn, wqkvT, woutT);
  gemm_qkv_kernel<<<dim3(24, MROWS / 128), 256, 0, stream>>>(xn, wqkvT, qbuf, kbuf, vtbuf);
  attn_kernel<<<dim3(BATCH * HEADS, NSEQ / 128), 512, 0, stream>>>(qbuf, kbuf, vtbuf, attnb);
  gemm_out_kernel<<<dim3(DIMM / 64, MROWS / 64), 256, 0, stream>>>(attnb, woutT, out);
}

// Round 8
// 177.542 us; speedup vs baseline: 1.0981x; 1.0174x over previous
//
#include <hip/hip_runtime.h>

// Fused: LayerNorm -> QKV proj -> per-head attention (diag masked) -> out proj
// B=2, N=2048, D=1024, H=16, dh=64. bf16 MFMA 16x16x32 everywhere.
// R18: prep LN restructured wave-per-row. Old: 4096 blocks x 256 thr, 4KB
//     read each, shfl+LDS+barrier 2-stage reduce (launch/latency-bound
//     shape). New: 1 row per WAVE (16 elem/lane, pure shfl_xor reduce, no
//     LDS/no barrier), 4 rows/block -> LN grid 1024, prep total 5120 blocks.
//     attn = R15 (best, 48.5-51 band), gemm_qkv / gemm_out (R17) untouched.

#define DIMM   1024
#define NSEQ   2048
#define BATCH  2
#define HEADS  16
#define DHEAD  64
#define QKVN   3072
#define MROWS  4096   // BATCH*NSEQ

typedef float          f32x4  __attribute__((ext_vector_type(4)));
typedef __bf16         bf16x8 __attribute__((ext_vector_type(8)));
typedef __bf16         bf16x4 __attribute__((ext_vector_type(4)));
typedef unsigned short u16x8  __attribute__((ext_vector_type(8)));
typedef unsigned short u16x4  __attribute__((ext_vector_type(4)));

// SCALE * log2(e): fold into q so softmax uses exp2 directly.
#define QSCALE (0.125f * 1.4426950408889634f)

#if __has_builtin(__builtin_amdgcn_exp2f)
#define EXP2(x) __builtin_amdgcn_exp2f(x)
#else
#define EXP2(x) exp2f(x)
#endif

__device__ __forceinline__ unsigned short f2bf(float f) {
  unsigned u = __builtin_bit_cast(unsigned, f);
  u += 0x7FFFu + ((u >> 16) & 1u);   // round-to-nearest-even
  return (unsigned short)(u >> 16);
}
__device__ __forceinline__ bf16x8 as_bf(u16x8 v) { return __builtin_bit_cast(bf16x8, v); }

// f32x4 -> 4 bf16 (RNE)
__device__ __forceinline__ u16x4 cvt4(f32x4 v) {
  bf16x4 b;
  b[0] = (__bf16)v[0]; b[1] = (__bf16)v[1]; b[2] = (__bf16)v[2]; b[3] = (__bf16)v[3];
  return __builtin_bit_cast(u16x4, b);
}

// async global->LDS, 16B per lane; LDS dest = wave-uniform base + lane*16
__device__ __forceinline__ void gl_lds16(const unsigned short* g, unsigned short* l) {
  __builtin_amdgcn_global_load_lds(
      (const __attribute__((address_space(1))) unsigned*)g,
      (__attribute__((address_space(3))) unsigned*)l, 16, 0, 0);
}

// swizzled b128 fragment read from an unpadded [rows][64] bf16 tile:
// LDS chunk c at row r holds global chunk c ^ (r&7).
__device__ __forceinline__ bf16x8 lds_frag(const unsigned short* base, int row, int chunk) {
  return as_bf(*(const u16x8*)&base[row * 64 + ((chunk ^ (row & 7)) << 3)]);
}

// same for [rows][128] bf16 tiles (16 chunks/row, 4-bit xor)
__device__ __forceinline__ bf16x8 lds_frag128(const unsigned short* base, int row, int chunk) {
  return as_bf(*(const u16x8*)&base[row * 128 + ((chunk ^ (row & 15)) << 3)]);
}

// ---------------- weight transpose tile + fp32->bf16: dst[c][r] = src[r][c]
__device__ __forceinline__ void transpose_tile(
    const float* __restrict__ src, unsigned short* __restrict__ dst,
    int R, int C, int bx, int by, int tid) {
  __shared__ float t[32][33];
  const int rb = by * 32, cb = bx * 32;
  const int r0 = tid >> 5;   // 0..7
  const int c  = tid & 31;
#pragma unroll
  for (int i = 0; i < 4; ++i)
    t[r0 + i * 8][c] = src[(rb + r0 + i * 8) * C + cb + c];
  __syncthreads();
#pragma unroll
  for (int i = 0; i < 4; ++i)
    dst[(cb + r0 + i * 8) * R + rb + c] = f2bf(t[c][r0 + i * 8]);
}

// ---------------- prep: LN (blocks 0..1023, one row per WAVE) +
// weight transposes (blocks 1024..5119)
__global__ __launch_bounds__(256) void prep_kernel(
    const float* __restrict__ x, const float* __restrict__ g,
    const float* __restrict__ be, const float* __restrict__ w_qkv,
    const float* __restrict__ w_out, unsigned short* __restrict__ xn,
    unsigned short* __restrict__ wqkvT, unsigned short* __restrict__ woutT) {
  const int bid = blockIdx.x, tid = threadIdx.x;
  if (bid < MROWS / 4) {
    // LayerNorm: one 1024-row per wave; lane handles 16 elems (4x float4).
    // Pure wave shfl reduce -- no LDS, no barrier.
    const int wave = tid >> 6, lane = tid & 63;
    const int row = bid * 4 + wave;
    float4 v[4];
    float s = 0.f, s2 = 0.f;
#pragma unroll
    for (int i = 0; i < 4; ++i) {
      v[i] = *(const float4*)&x[row * DIMM + i * 256 + lane * 4];
      s  += v[i].x + v[i].y + v[i].z + v[i].w;
      s2 += v[i].x * v[i].x + v[i].y * v[i].y + v[i].z * v[i].z + v[i].w * v[i].w;
    }
#pragma unroll
    for (int o = 32; o >= 1; o >>= 1) { s += __shfl_xor(s, o); s2 += __shfl_xor(s2, o); }
    const float mu  = s * (1.0f / DIMM);
    const float var = s2 * (1.0f / DIMM) - mu * mu;
    const float rs  = rsqrtf(var + 1e-5f);
#pragma unroll
    for (int i = 0; i < 4; ++i) {
      const float4 gg = *(const float4*)&g[i * 256 + lane * 4];
      const float4 bb = *(const float4*)&be[i * 256 + lane * 4];
      u16x4 o;
      o[0] = f2bf((v[i].x - mu) * rs * gg.x + bb.x);
      o[1] = f2bf((v[i].y - mu) * rs * gg.y + bb.y);
      o[2] = f2bf((v[i].z - mu) * rs * gg.z + bb.z);
      o[3] = f2bf((v[i].w - mu) * rs * gg.w + bb.w);
      *(u16x4*)&xn[row * DIMM + i * 256 + lane * 4] = o;
    }
  } else {
    const int t = bid - MROWS / 4;        // 0..4095
    const int bx = t & 127, by = t >> 7;  // 128 x 32
    if (bx < QKVN / 32) transpose_tile(w_qkv, wqkvT, DIMM, QKVN, bx, by, tid);
    else                transpose_tile(w_out, woutT, DIMM, DIMM, bx - QKVN / 32, by, tid);
  }
}

// ---------------- merged QKV GEMM: 128x128 tiles, single-buffer 32KB LDS,
// 3 blocks/CU co-resident (grid 768). bn 0..15 -> q/k (C^T), 16..23 -> v (C).
__global__ __launch_bounds__(256, 3) void gemm_qkv_kernel(
    const unsigned short* __restrict__ A, const unsigned short* __restrict__ Bt,
    unsigned short* __restrict__ qb, unsigned short* __restrict__ kb,
    unsigned short* __restrict__ vtb) {
  __shared__ __attribute__((aligned(16))) unsigned short As[128 * 64];  // 16 KB
  __shared__ __attribute__((aligned(16))) unsigned short Bs[128 * 64];  // 16 KB
  const int tid = threadIdx.x;
  const int bm = blockIdx.y, bn = blockIdx.x;
  const int lane = tid & 63, wave = tid >> 6;
  const int l15 = lane & 15, quad = lane >> 4;
  const int wm = wave >> 1, wn = wave & 1;
  const int lrow = lane >> 3;
  const int gcol = ((lane & 7) ^ lrow) << 3;
  const unsigned short* Ab = A  + (bm * 128 + wave * 32 + lrow) * DIMM + gcol;
  const unsigned short* Bb = Bt + (bn * 128 + wave * 32 + lrow) * DIMM + gcol;
  const bool swap = (bn < 16);
  f32x4 acc[4][4] = {};

  for (int k0 = 0; k0 < DIMM; k0 += 64) {
#pragma unroll
    for (int j = 0; j < 4; ++j) {
      gl_lds16(Ab + j * 8 * DIMM + k0, &As[(wave * 32 + j * 8) * 64]);
      gl_lds16(Bb + j * 8 * DIMM + k0, &Bs[(wave * 32 + j * 8) * 64]);
    }
    __syncthreads();
#pragma unroll
    for (int kk = 0; kk < 2; ++kk) {
      bf16x8 af[4], bfr[4];
#pragma unroll
      for (int mi = 0; mi < 4; ++mi) af[mi]  = lds_frag(As, wm * 64 + mi * 16 + l15, kk * 4 + quad);
#pragma unroll
      for (int ni = 0; ni < 4; ++ni) bfr[ni] = lds_frag(Bs, wn * 64 + ni * 16 + l15, kk * 4 + quad);
      if (swap) {
#pragma unroll
        for (int mi = 0; mi < 4; ++mi)
#pragma unroll
          for (int ni = 0; ni < 4; ++ni)
            acc[mi][ni] = __builtin_amdgcn_mfma_f32_16x16x32_bf16(bfr[ni], af[mi], acc[mi][ni], 0, 0, 0);
      } else {
#pragma unroll
        for (int mi = 0; mi < 4; ++mi)
#pragma unroll
          for (int ni = 0; ni < 4; ++ni)
            acc[mi][ni] = __builtin_amdgcn_mfma_f32_16x16x32_bf16(af[mi], bfr[ni], acc[mi][ni], 0, 0, 0);
      }
    }
    __syncthreads();
  }

  if (swap) {
    // q/k blocks: C^T -> reg r runs along weight col (dd) -> b64 stores.
    const int colbase = bn * 128 + wn * 64;        // wave-uniform
    const int which = colbase >> 10;               // 0=q, 1=k
    unsigned short* dst = which ? kb : qb;
    const float sc = which ? 1.0f : QSCALE;
#pragma unroll
    for (int mi = 0; mi < 4; ++mi) {
      const int m = bm * 128 + wm * 64 + mi * 16 + l15;   // xn row
      const int bh0 = (m >> 11) * HEADS;
      const int n = m & 2047;
#pragma unroll
      for (int ni = 0; ni < 4; ++ni) {
        const int wc = (colbase & 1023) + ni * 16 + quad * 4;  // r-contig
        const int h = wc >> 6, dd = wc & 63;
        f32x4 v = acc[mi][ni] * sc;
        *(u16x4*)&dst[((bh0 + h) * NSEQ + n) * DHEAD + dd] = cvt4(v);
      }
    }
  } else {
    // v blocks: C -> reg r runs along n -> b64 stores to vt.
    const int colbase = bn * 128 + wn * 64 - 2048;   // v col base, 0..1023
#pragma unroll
    for (int mi = 0; mi < 4; ++mi) {
      const int m0 = bm * 128 + wm * 64 + mi * 16 + quad * 4;   // n, r-contig
      const int bh0 = (m0 >> 11) * HEADS;
      const int n0 = m0 & 2047;
#pragma unroll
      for (int ni = 0; ni < 4; ++ni) {
        const int vcol = colbase + ni * 16 + l15;
        const int h = vcol >> 6, dd = vcol & 63;
        *(u16x4*)&vtb[((bh0 + h) * DHEAD + dd) * NSEQ + n0] = cvt4(acc[mi][ni]);
      }
    }
  }
}

// ---------------- flash attention, transposed-S, fixed-offset softmax.
// R15 (best known): block = (bh, 128-row q tile), 512 threads / 8 waves,
// 2 blocks/CU -> 4 waves/SIMD. wave = (ikv = wave>>2, jq = wave&3):
// 32 kv x 32 q slice. Double-buffered K/V, ONE barrier per kv-iter.
// p = exp2(s-32); scale cancels. Epilogue: 2-way cross-wave (ikv) O/lsum
// reduction in dead K/V LDS.
__global__ __launch_bounds__(512, 4) void attn_kernel(
    const unsigned short* __restrict__ qb, const unsigned short* __restrict__ kb,
    const unsigned short* __restrict__ vtb, unsigned short* __restrict__ attn_out) {
  __shared__ __attribute__((aligned(16))) unsigned short KVs[4][64 * 64]; // K0,K1,Vt0,Vt1 (swizzled)
  __shared__ __attribute__((aligned(16))) unsigned short Ps[8][32][36];   // per-wave P slice
  __shared__ float Lred[4][2][16];
  const int tid = threadIdx.x, wave = tid >> 6, lane = tid & 63;
  const int l15 = lane & 15, quad = lane >> 4;
  const int bh = blockIdx.x, qt = blockIdx.y;
  const int b = bh >> 4, h = bh & 15;
  const int jq = wave & 3;    // q 32-row slice
  const int ikv = wave >> 2;  // kv-half (32 rows of the 64-tile)
  const int qbase = qt * 128 + jq * 32;

  // Q fragments for this wave's 32 q rows (B-operand: n=l15=q, k=quad*8+e)
  bf16x8 aq[2][2];
#pragma unroll
  for (int nt = 0; nt < 2; ++nt) {
    const unsigned short* qrow = qb + (bh * NSEQ + qbase + nt * 16 + l15) * DHEAD;
    aq[nt][0] = as_bf(*(const u16x8*)(qrow + quad * 8));
    aq[nt][1] = as_bf(*(const u16x8*)(qrow + 32 + quad * 8));
  }

  float lsum[2] = {0.f, 0.f};
  f32x4 occ[4][2] = {};   // partial O^T: [ct: d=ct*16+quad*4+r][nt: q=nt*16+l15]

  // staging: each of 8 waves stages 8 rows (1 gl_lds16) of K and of Vt
  const int lrow = lane >> 3;
  const int gcol = ((lane & 7) ^ lrow) << 3;
  const unsigned short* Kb = kb  + (bh * NSEQ + wave * 8 + lrow) * DHEAD + gcol;
  const unsigned short* Vb = vtb + (bh * DHEAD + wave * 8 + lrow) * NSEQ + gcol;

  // prologue: stage kv tile 0 into buffer 0 (K -> KVs[0], Vt -> KVs[2])
  gl_lds16(Kb, &KVs[0][(wave * 8) * 64]);
  gl_lds16(Vb, &KVs[2][(wave * 8) * 64]);

  // diagonal: global q == global kv. q = qt*128 + jq*32 + nt*16 + l15,
  // kv = it*64 + ikv*32 + mt*16 + quad*4 + r. Hit iff it == qt*2 + (jq>>1),
  // ikv == (jq&1), mt == nt, quad*4+r == l15.
  const int diag_it = qt * 2 + (jq >> 1);
  const bool diag_wave = (ikv == (jq & 1));

  for (int it = 0; it < NSEQ / 64; ++it) {
    const int cur = it & 1;
    __syncthreads();   // drains this wave's async loads into buf[cur]
    if (it < NSEQ / 64 - 1) {
      gl_lds16(Kb + (it + 1) * 64 * DHEAD, &KVs[cur ^ 1][(wave * 8) * 64]);
      gl_lds16(Vb + (it + 1) * 64,         &KVs[2 + (cur ^ 1)][(wave * 8) * 64]);
    }
    // fragments: only this wave's kv-half
    bf16x8 ak[2][2];   // [kk][mt]: K rows ikv*32+mt*16+l15, d chunk kk*4+quad
#pragma unroll
    for (int kk = 0; kk < 2; ++kk)
#pragma unroll
      for (int mt = 0; mt < 2; ++mt)
        ak[kk][mt] = lds_frag(&KVs[cur][0], ikv * 32 + mt * 16 + l15, kk * 4 + quad);
    bf16x8 av[4];      // [ct]: Vt rows d=ct*16+l15, kv chunk ikv*4+quad
#pragma unroll
    for (int ct = 0; ct < 4; ++ct)
      av[ct] = lds_frag(&KVs[2 + cur][0], ct * 16 + l15, ikv * 4 + quad);

    // ---- QK^T: S^T slice 32kv x 32q, 8 MFMA ----
    f32x4 scc[2][2];
#pragma unroll
    for (int mt = 0; mt < 2; ++mt)
#pragma unroll
      for (int nt = 0; nt < 2; ++nt) scc[mt][nt] = (f32x4){-32.f, -32.f, -32.f, -32.f};
    __builtin_amdgcn_s_setprio(1);
#pragma unroll
    for (int kk = 0; kk < 2; ++kk)
#pragma unroll
      for (int mt = 0; mt < 2; ++mt)
#pragma unroll
        for (int nt = 0; nt < 2; ++nt)
          scc[mt][nt] = __builtin_amdgcn_mfma_f32_16x16x32_bf16(ak[kk][mt], aq[nt][kk], scc[mt][nt], 0, 0, 0);
    __builtin_amdgcn_s_setprio(0);

#pragma unroll
    for (int mt = 0; mt < 2; ++mt)
#pragma unroll
      for (int nt = 0; nt < 2; ++nt)
#pragma unroll
        for (int r = 0; r < 4; ++r) scc[mt][nt][r] = EXP2(scc[mt][nt][r]);

    // diagonal mask (wave-uniform branch; zero BEFORE summing)
    if (it == diag_it && diag_wave) {
#pragma unroll
      for (int nt = 0; nt < 2; ++nt)
#pragma unroll
        for (int r = 0; r < 4; ++r)
          if (quad * 4 + r == l15) scc[nt][nt][r] = 0.f;
    }

#pragma unroll
    for (int nt = 0; nt < 2; ++nt) {
      f32x4 t = scc[0][nt] + scc[1][nt];
      lsum[nt] += (t[0] + t[1]) + (t[2] + t[3]);
    }

    // ---- P -> LDS (wave-private slice, same-wave in-order) ----
    // row q (0..31) = nt*16+l15, col kv (0..31) = mt*16+quad*4
#pragma unroll
    for (int mt = 0; mt < 2; ++mt)
#pragma unroll
      for (int nt = 0; nt < 2; ++nt)
        *(u16x4*)&Ps[wave][nt * 16 + l15][mt * 16 + quad * 4] = cvt4(scc[mt][nt]);

    bf16x8 bp[2];
#pragma unroll
    for (int nt = 0; nt < 2; ++nt)
      bp[nt] = as_bf(*(const u16x8*)&Ps[wave][nt * 16 + l15][quad * 8]);

    // ---- PV: partial O^T over this kv-half, 8 MFMA (K=32) ----
    __builtin_amdgcn_s_setprio(1);
#pragma unroll
    for (int ct = 0; ct < 4; ++ct)
#pragma unroll
      for (int nt = 0; nt < 2; ++nt)
        occ[ct][nt] = __builtin_amdgcn_mfma_f32_16x16x32_bf16(av[ct], bp[nt], occ[ct][nt], 0, 0, 0);
    __builtin_amdgcn_s_setprio(0);
  }

  // within-wave lsum reduction over quads (kv sub-slices)
#pragma unroll
  for (int nt = 0; nt < 2; ++nt) {
    lsum[nt] += __shfl_xor(lsum[nt], 16);
    lsum[nt] += __shfl_xor(lsum[nt], 32);
  }

  // ---- 2-way cross-wave reduction: ikv=1 partials added into ikv=0 ----
  __syncthreads();                       // all compute done; K/V LDS dead
  float* Ored = (float*)&KVs[0][0];      // 32 KB overlay: 8 KB per jq
  if (ikv == 1) {
#pragma unroll
    for (int ct = 0; ct < 4; ++ct)
#pragma unroll
      for (int nt = 0; nt < 2; ++nt)
        *(f32x4*)&Ored[((jq * 8 + ct * 2 + nt) * 64 + lane) * 4] = occ[ct][nt];
    if (quad == 0) {
#pragma unroll
      for (int nt = 0; nt < 2; ++nt) Lred[jq][nt][l15] = lsum[nt];
    }
  }
  __syncthreads();
  if (ikv == 0) {
#pragma unroll
    for (int ct = 0; ct < 4; ++ct)
#pragma unroll
      for (int nt = 0; nt < 2; ++nt)
        occ[ct][nt] += *(const f32x4*)&Ored[((jq * 8 + ct * 2 + nt) * 64 + lane) * 4];
#pragma unroll
    for (int nt = 0; nt < 2; ++nt) {
      const float l = lsum[nt] + Lred[jq][nt][l15];
      const float rl = __builtin_amdgcn_rcpf(l);
      const int qg = qbase + nt * 16 + l15;
#pragma unroll
      for (int ct = 0; ct < 4; ++ct) {
        f32x4 ov = occ[ct][nt] * rl;
        *(u16x4*)&attn_out[(b * NSEQ + qg) * DIMM + h * DHEAD + ct * 16 + quad * 4] = cvt4(ov);
      }
    }
  }
}

// ---------------- output projection (C^T): [4096,1024] @ woutT[1024,1024] -> fp32
// R17: M64 x N64 tiles, BK=128 (8 K-iters), 32KB LDS, grid (16,64)=1024 =
// 4 blocks/CU = 16 waves/CU = 4 waves/SIMD.
__global__ __launch_bounds__(256, 4) void gemm_out_kernel(
    const unsigned short* __restrict__ A,   // attn bf16 [4096,1024]
    const unsigned short* __restrict__ Bt,  // woutT bf16 [1024,1024]
    float* __restrict__ out) {
  __shared__ __attribute__((aligned(16))) unsigned short As[64 * 128];   // 16 KB
  __shared__ __attribute__((aligned(16))) unsigned short Bs[64 * 128];   // 16 KB
  const int tid = threadIdx.x;
  const int bm = blockIdx.y, bn = blockIdx.x;
  const int lane = tid & 63, wave = tid >> 6;
  const int l15 = lane & 15, quad = lane >> 4;
  const int wm = wave >> 1, wn = wave & 1;
  // staging lane mapping for 256B rows: 4 rows per gl_lds16
  const int rl4 = lane >> 4;   // row within instr, 0..3
  const int cp  = lane & 15;   // chunk position, 0..15
  const int cx  = cp ^ rl4;    // base xor (LDS[row][p] = G[row][p ^ (row&15)])
  const int Arow0 = bm * 64 + wave * 16 + rl4;
  const int Brow0 = bn * 64 + wave * 16 + rl4;
  f32x4 acc[2][2] = {};

  for (int it = 0; it < 8; ++it) {
    const int k0 = it * 128;
    // stage A: 64 rows x 128k (4 instrs/wave), B: 64 rows (4 instrs/wave)
#pragma unroll
    for (int j = 0; j < 4; ++j)
      gl_lds16(A + (Arow0 + j * 4) * DIMM + k0 + ((cx ^ (j << 2)) << 3),
               &As[(wave * 16 + j * 4) * 128]);
#pragma unroll
    for (int j = 0; j < 4; ++j)
      gl_lds16(Bt + (Brow0 + j * 4) * DIMM + k0 + ((cx ^ (j << 2)) << 3),
               &Bs[(wave * 16 + j * 4) * 128]);
    __syncthreads();
#pragma unroll
    for (int kk = 0; kk < 4; ++kk) {
      bf16x8 af[2], bfr[2];
#pragma unroll
      for (int mi = 0; mi < 2; ++mi) af[mi]  = lds_frag128(As, wm * 32 + mi * 16 + l15, kk * 4 + quad);
#pragma unroll
      for (int ni = 0; ni < 2; ++ni) bfr[ni] = lds_frag128(Bs, wn * 32 + ni * 16 + l15, kk * 4 + quad);
#pragma unroll
      for (int mi = 0; mi < 2; ++mi)
#pragma unroll
        for (int ni = 0; ni < 2; ++ni)
          acc[mi][ni] = __builtin_amdgcn_mfma_f32_16x16x32_bf16(bfr[ni], af[mi], acc[mi][ni], 0, 0, 0);
    }
    __syncthreads();
  }
  // C^T epilogue: col=l15 -> out row m; row(quad*4+r, r-contig) -> out col.
#pragma unroll
  for (int mi = 0; mi < 2; ++mi) {
    const int m = bm * 64 + wm * 32 + mi * 16 + l15;   // attn row
#pragma unroll
    for (int ni = 0; ni < 2; ++ni) {
      const int col = bn * 64 + wn * 32 + ni * 16 + quad * 4;  // r-contig
      *(f32x4*)&out[m * DIMM + col] = acc[mi][ni];
    }
  }
}

extern "C" void kernel_launch(void* const* d_in, const int* in_sizes, int n_in,
                              void* d_out, int out_size, void* d_ws, size_t ws_size,
                              hipStream_t stream) {
  const float* x     = (const float*)d_in[0];
  const float* gamma = (const float*)d_in[1];
  const float* beta  = (const float*)d_in[2];
  const float* w_qkv = (const float*)d_in[3];  // [1024, 3072]
  const float* w_out = (const float*)d_in[4];  // [1024, 1024]
  float* out = (float*)d_out;

  char* ws = (char*)d_ws;
  unsigned short* xn    = (unsigned short*)(ws);                        // 8 MB
  unsigned short* wqkvT = (unsigned short*)(ws + 8388608);              // 6 MB
  unsigned short* woutT = (unsigned short*)(ws + 14680064);             // 2 MB
  unsigned short* qbuf  = (unsigned short*)(ws + 16777216);             // 8 MB
  unsigned short* kbuf  = (unsigned short*)(ws + 25165824);             // 8 MB
  unsigned short* vtbuf = (unsigned short*)(ws + 33554432);             // 8 MB
  unsigned short* attnb = (unsigned short*)(ws + 41943040);             // 8 MB

  prep_kernel<<<MROWS / 4 + (QKVN + DIMM) / 32 * (DIMM / 32), 256, 0, stream>>>(
      x, gamma, beta, w_qkv, w_out, xn, wqkvT, woutT);
  gemm_qkv_kernel<<<dim3(24, MROWS / 128), 256, 0, stream>>>(xn, wqkvT, qbuf, kbuf, vtbuf);
  attn_kernel<<<dim3(BATCH * HEADS, NSEQ / 128), 512, 0, stream>>>(qbuf, kbuf, vtbuf, attnb);
  gemm_out_kernel<<<dim3(DIMM / 64, MROWS / 64), 256, 0, stream>>>(attnb, woutT, out);
}